// Round 6
// baseline (165.769 us; speedup 1.0000x reference)
//
#include <hip/hip_runtime.h>
#include <math.h>

// DRMM pipeline for MI355X (gfx950) — round 6: wave-split half-rows for 2x
// concurrency.
// Phase 1: 1024 blocks x 512 thr (32 waves/CU). Block = 256 tokens.
//   Waves 0-3 stream row elements [0,64), waves 4-7 stream [64,128) of the
//   SAME 256 tokens. Query loads stay wave-uniform (scalar s_load path).
//   Partials (dd,dq[8]) combined via LDS (stride 9 -> conflict-free), then
//   half-0 waves bin into per-subgroup LDS hists. Partials to d_ws.
// Phase 2: MLP 30->128->64->32->1 + gate softmax + output. 512 blocks x 512 thr.
// B=32, D=16, L=512, Q=8, E=128, NB=30

#define BN_INV 0.99950037468777346f  // np.float32(1/sqrt(1+1e-3))

__device__ __forceinline__ float shflx(float v, int m) {
    return __shfl_xor(v, m, 64);
}

__device__ __forceinline__ int sel8i(int v0, int v1, int v2, int v3,
                                     int v4, int v5, int v6, int v7, int i) {
    int a0 = (i & 1) ? v1 : v0;
    int a1 = (i & 1) ? v3 : v2;
    int a2 = (i & 1) ? v5 : v4;
    int a3 = (i & 1) ? v7 : v6;
    int b0 = (i & 2) ? a1 : a0;
    int b1 = (i & 2) ? a3 : a2;
    return (i & 4) ? b1 : b0;
}

// fast tanh: clamp(+-9) then (e^2x-1)/(e^2x+1) via hw exp2 + rcp.
// rel err ~2e-7; tanh(9) == 1.0f to fp32 so clamp is exact.
__device__ __forceinline__ float tanh_fast(float x) {
    float y = fminf(fmaxf(x, -9.0f), 9.0f);
    float t = exp2f(y * 2.8853901817f);      // e^(2y)
    return (t - 1.0f) * __builtin_amdgcn_rcpf(t + 1.0f);
}

// ---------------- Phase 1: gather + histogram (wave-split half-rows) --------
template <bool PARTIAL>
__global__ __launch_bounds__(512, 8)
void drmm_hist(const int* __restrict__ doc,
               const int* __restrict__ query,
               const float* __restrict__ emb,
               float* __restrict__ hist_out)
{
    __shared__ float histw[4][8][32];   // [subgroup][q][bin(+2 pad)]
    __shared__ float comb[4][64][9];    // half-1 partials (stride 9: no conflicts)
    __shared__ float qn_s[8];

    const int tid  = threadIdx.x;
    const int bid  = blockIdx.x;        // (bd, token-half): 0..1023
    const int b    = bid >> 5;          // batch
    const int wid  = tid >> 6;          // 0..7
    const int lane = tid & 63;
    const int sub  = wid & 3;           // token subgroup 0..3
    const int half = wid >> 2;          // element half 0/1

    for (int i = tid; i < 4 * 8 * 32; i += 512) ((float*)histw)[i] = 0.0f;

    // wave-uniform query row indices
    const int* qrow = query + b * 8;
    const int qi0 = __builtin_amdgcn_readfirstlane(qrow[0]);
    const int qi1 = __builtin_amdgcn_readfirstlane(qrow[1]);
    const int qi2 = __builtin_amdgcn_readfirstlane(qrow[2]);
    const int qi3 = __builtin_amdgcn_readfirstlane(qrow[3]);
    const int qi4 = __builtin_amdgcn_readfirstlane(qrow[4]);
    const int qi5 = __builtin_amdgcn_readfirstlane(qrow[5]);
    const int qi6 = __builtin_amdgcn_readfirstlane(qrow[6]);
    const int qi7 = __builtin_amdgcn_readfirstlane(qrow[7]);

    const int hoff = half * 64;  // element offset for this wave
    const float4* qf0 = (const float4*)(emb + (size_t)qi0 * 128 + hoff);
    const float4* qf1 = (const float4*)(emb + (size_t)qi1 * 128 + hoff);
    const float4* qf2 = (const float4*)(emb + (size_t)qi2 * 128 + hoff);
    const float4* qf3 = (const float4*)(emb + (size_t)qi3 * 128 + hoff);
    const float4* qf4 = (const float4*)(emb + (size_t)qi4 * 128 + hoff);
    const float4* qf5 = (const float4*)(emb + (size_t)qi5 * 128 + hoff);
    const float4* qf6 = (const float4*)(emb + (size_t)qi6 * 128 + hoff);
    const float4* qf7 = (const float4*)(emb + (size_t)qi7 * 128 + hoff);

    // query norms: wave 0 (same op order as round 5, which passed absmax 0.0)
    if (wid == 0) {
        int q = lane >> 3, j = lane & 7;
        int qis = sel8i(qi0, qi1, qi2, qi3, qi4, qi5, qi6, qi7, q);
        const float4* qq = (const float4*)(emb + (size_t)qis * 128) + j * 4;
        float s = 0.f;
#pragma unroll
        for (int c = 0; c < 4; ++c) {
            float4 x = qq[c];
            s = fmaf(x.x, x.x, s); s = fmaf(x.y, x.y, s);
            s = fmaf(x.z, x.z, s); s = fmaf(x.w, x.w, s);
        }
        s += shflx(s, 1); s += shflx(s, 2); s += shflx(s, 4);
        if (j == 0) qn_s[q] = sqrtf(s);
    }

    // ---- per-lane half-row streaming: 16 x float4 = 256 B ----
    const int gtok = bid * 256 + sub * 64 + lane;     // 0..262143
    const int idx  = doc[gtok];
    const float4* rp = (const float4*)(emb + (size_t)idx * 128 + hoff);

    float dd = 0.f;
    float dq0 = 0.f, dq1 = 0.f, dq2 = 0.f, dq3 = 0.f;
    float dq4 = 0.f, dq5 = 0.f, dq6 = 0.f, dq7 = 0.f;

#pragma unroll 4
    for (int s = 0; s < 16; ++s) {
        float4 v  = rp[s];
        float4 a0 = qf0[s], a1 = qf1[s], a2 = qf2[s], a3 = qf3[s];
        float4 a4 = qf4[s], a5 = qf5[s], a6 = qf6[s], a7 = qf7[s];
        dd  = fmaf(v.x, v.x, dd);  dd  = fmaf(v.y, v.y, dd);
        dd  = fmaf(v.z, v.z, dd);  dd  = fmaf(v.w, v.w, dd);
#define ACC(A, Dq) Dq = fmaf(v.x, A.x, Dq); Dq = fmaf(v.y, A.y, Dq); \
                   Dq = fmaf(v.z, A.z, Dq); Dq = fmaf(v.w, A.w, Dq);
        ACC(a0, dq0) ACC(a1, dq1) ACC(a2, dq2) ACC(a3, dq3)
        ACC(a4, dq4) ACC(a5, dq5) ACC(a6, dq6) ACC(a7, dq7)
#undef ACC
    }

    // half-1 waves deposit partials; half-0 waves combine and bin.
    if (half == 1) {
        float* c = comb[sub][lane];
        c[0] = dd;
        c[1] = dq0; c[2] = dq1; c[3] = dq2; c[4] = dq3;
        c[5] = dq4; c[6] = dq5; c[7] = dq6; c[8] = dq7;
    }
    __syncthreads();

    if (half == 0) {
        const float* c = comb[sub][lane];
        dd  += c[0];
        dq0 += c[1]; dq1 += c[2]; dq2 += c[3]; dq3 += c[4];
        dq4 += c[5]; dq5 += c[6]; dq6 += c[7]; dq7 += c[8];

        const float dn = sqrtf(dd);
#define DOBIN(J, DQ) {                                                  \
        float sim = DQ / (dn * qn_s[J] + 1e-8f);                        \
        float u = (sim - 0.001f) / 0.999f * 30.0f;                      \
        int bin = (int)floorf(u);                                       \
        bin = bin < 0 ? 0 : (bin > 29 ? 29 : bin);                      \
        atomicAdd(&histw[sub][J][bin], 1.0f);                           \
    }
        DOBIN(0, dq0) DOBIN(1, dq1) DOBIN(2, dq2) DOBIN(3, dq3)
        DOBIN(4, dq4) DOBIN(5, dq5) DOBIN(6, dq6) DOBIN(7, dq7)
#undef DOBIN
    }
    __syncthreads();

    // flush 8q x 30 bins (exact integer counts)
    if (tid < 240) {
        int q = tid / 30, k = tid - q * 30;
        float s = histw[0][q][k] + histw[1][q][k]
                + histw[2][q][k] + histw[3][q][k];
        if (PARTIAL) {
            hist_out[(size_t)bid * 240 + tid] = s;
        } else {
            atomicAdd(&hist_out[(bid >> 1) * 240 + tid], s);
        }
    }
}

// ---------------- Phase 2: gate softmax + MLP + output ----------------
template <bool PARTIAL>
__global__ __launch_bounds__(512, 4)
void drmm_mlp(const float* __restrict__ hist_g,
              const int* __restrict__ query,
              const float* __restrict__ idf,
              const float* __restrict__ w_gate,
              const float* __restrict__ g_in, const float* __restrict__ b_in,
              const float* __restrict__ W0, const float* __restrict__ b0,
              const float* __restrict__ g0, const float* __restrict__ be0,
              const float* __restrict__ W1, const float* __restrict__ b1,
              const float* __restrict__ g1, const float* __restrict__ be1,
              const float* __restrict__ W2, const float* __restrict__ b2,
              const float* __restrict__ g2, const float* __restrict__ be2,
              const float* __restrict__ W3, const float* __restrict__ b3,
              const float* __restrict__ g3, const float* __restrict__ be3,
              float* __restrict__ out)
{
    __shared__ float xrow[8][30];
    __shared__ float h1s[8][128];
    __shared__ float h2s[8][64];
    __shared__ float h3s[8][32];
    __shared__ float gate_s[8];
    __shared__ float part[8];

    const int tid  = threadIdx.x;
    const int bd   = blockIdx.x;
    const int b    = bd >> 4;
    const int wid  = tid >> 6;
    const int lane = tid & 63;

    // Gate softmax: 8 parallel lanes (same op order as rounds 2-5).
    if (tid >= 504) {
        int q = tid - 504;
        float z = w_gate[q] * idf[query[b * 8 + q]];
        float m = z;
        m = fmaxf(m, shflx(m, 1)); m = fmaxf(m, shflx(m, 2)); m = fmaxf(m, shflx(m, 4));
        float e = expf(z - m);
        float s = e;
        s += shflx(s, 1); s += shflx(s, 2); s += shflx(s, 4);
        gate_s[q] = e / s;
    }

    if (tid < 240) {
        int q = tid / 30, k = tid - q * 30;
        float s;
        if (PARTIAL) {
            const float* hp = hist_g + (size_t)bd * 480 + tid;
            s = hp[0] + hp[240];  // exact int counts
        } else {
            s = hist_g[bd * 240 + tid];
        }
        xrow[q][k] = g_in[k] * (s * BN_INV) + b_in[k];
    }
    __syncthreads();

    // layer 1: 30 -> 128 (lane j computes outputs j and j+64); wave wid = q
    {
        float a0 = 0.f, a1 = 0.f;
#pragma unroll
        for (int k = 0; k < 30; ++k) {
            float xk = xrow[wid][k];
            a0 += xk * W0[k * 128 + lane];
            a1 += xk * W0[k * 128 + 64 + lane];
        }
        a0 += b0[lane]; a1 += b0[lane + 64];
        h1s[wid][lane]      = tanh_fast(g0[lane]      * (a0 * BN_INV) + be0[lane]);
        h1s[wid][lane + 64] = tanh_fast(g0[lane + 64] * (a1 * BN_INV) + be0[lane + 64]);
    }
    __syncthreads();

    // layer 2: 128 -> 64
    {
        float a = 0.f;
#pragma unroll 8
        for (int k = 0; k < 128; ++k) a += h1s[wid][k] * W1[k * 64 + lane];
        a += b1[lane];
        h2s[wid][lane] = tanh_fast(g1[lane] * (a * BN_INV) + be1[lane]);
    }
    __syncthreads();

    // layer 3: 64 -> 32
    if (lane < 32) {
        float a = 0.f;
#pragma unroll 8
        for (int k = 0; k < 64; ++k) a += h2s[wid][k] * W2[k * 32 + lane];
        a += b2[lane];
        h3s[wid][lane] = tanh_fast(g2[lane] * (a * BN_INV) + be2[lane]);
    }
    __syncthreads();

    // layer 4: 32 -> 1, gate weighting
    if (lane == 0) {
        float a = 0.f;
#pragma unroll
        for (int k = 0; k < 32; ++k) a += h3s[wid][k] * W3[k];
        a += b3[0];
        float y = tanh_fast(g3[0] * (a * BN_INV) + be3[0]);
        part[wid] = gate_s[wid] * y;
    }
    __syncthreads();

    if (tid == 0) {
        float s = 0.f;
#pragma unroll
        for (int q = 0; q < 8; ++q) s += part[q];
        out[bd] = s;
    }
}

extern "C" void kernel_launch(void* const* d_in, const int* in_sizes, int n_in,
                              void* d_out, int out_size, void* d_ws, size_t ws_size,
                              hipStream_t stream) {
    (void)in_sizes; (void)n_in; (void)out_size;
    const int*   doc    = (const int*)d_in[0];
    const int*   query  = (const int*)d_in[1];
    const float* emb    = (const float*)d_in[2];
    const float* idf    = (const float*)d_in[3];
    const float* w_gate = (const float*)d_in[4];
    const float* g_in   = (const float*)d_in[5];
    const float* b_in   = (const float*)d_in[6];
    const float* W0  = (const float*)d_in[7];
    const float* b0  = (const float*)d_in[8];
    const float* g0  = (const float*)d_in[9];
    const float* be0 = (const float*)d_in[10];
    const float* W1  = (const float*)d_in[11];
    const float* b1  = (const float*)d_in[12];
    const float* g1  = (const float*)d_in[13];
    const float* be1 = (const float*)d_in[14];
    const float* W2  = (const float*)d_in[15];
    const float* b2  = (const float*)d_in[16];
    const float* g2  = (const float*)d_in[17];
    const float* be2 = (const float*)d_in[18];
    const float* W3  = (const float*)d_in[19];
    const float* b3  = (const float*)d_in[20];
    const float* g3  = (const float*)d_in[21];
    const float* be3 = (const float*)d_in[22];

    float* hist_g = (float*)d_ws;
    const size_t need_partial = (size_t)1024 * 240 * sizeof(float); // 983 KB

    if (ws_size >= need_partial) {
        drmm_hist<true><<<dim3(1024), dim3(512), 0, stream>>>(doc, query, emb, hist_g);
        drmm_mlp<true><<<dim3(512), dim3(512), 0, stream>>>(
            hist_g, query, idf, w_gate, g_in, b_in,
            W0, b0, g0, be0, W1, b1, g1, be1,
            W2, b2, g2, be2, W3, b3, g3, be3, (float*)d_out);
    } else {
        hipMemsetAsync(hist_g, 0, 512 * 240 * sizeof(float), stream);
        drmm_hist<false><<<dim3(1024), dim3(512), 0, stream>>>(doc, query, emb, hist_g);
        drmm_mlp<false><<<dim3(512), dim3(512), 0, stream>>>(
            hist_g, query, idf, w_gate, g_in, b_in,
            W0, b0, g0, be0, W1, b1, g1, be1,
            W2, b2, g2, be2, W3, b3, g3, be3, (float*)d_out);
    }
}

// Round 7
// 50.694 us; speedup vs baseline: 3.2700x; 3.2700x over previous
//
#include <hip/hip_runtime.h>
#include <math.h>

// DRMM pipeline for MI355X (gfx950) — round 7: R5 lane-owns-token structure
// + explicit 8-deep load pipeline (more independent lines in flight per wave).
// Phase 1: 1024 blocks x 256 thr; lane = one doc token; streams its 512B row
//   as 4 chunks of 8 float4 with ping-pong prefetch (8-16 loads outstanding).
//   Query rows via wave-uniform scalarized loads (readfirstlane indices).
// Phase 2: MLP 30->128->64->32->1 + gate softmax + output. 512 blocks x 512 thr.
// B=32, D=16, L=512, Q=8, E=128, NB=30

#define BN_INV 0.99950037468777346f  // np.float32(1/sqrt(1+1e-3))

__device__ __forceinline__ float shflx(float v, int m) {
    return __shfl_xor(v, m, 64);
}

__device__ __forceinline__ int sel8i(int v0, int v1, int v2, int v3,
                                     int v4, int v5, int v6, int v7, int i) {
    int a0 = (i & 1) ? v1 : v0;
    int a1 = (i & 1) ? v3 : v2;
    int a2 = (i & 1) ? v5 : v4;
    int a3 = (i & 1) ? v7 : v6;
    int b0 = (i & 2) ? a1 : a0;
    int b1 = (i & 2) ? a3 : a2;
    return (i & 4) ? b1 : b0;
}

// fast tanh: clamp(+-9) then (e^2x-1)/(e^2x+1) via hw exp2 + rcp.
// tanh(9)==1.0f in fp32 so the clamp is exact; rel err ~2e-7. (R6: absmax 0.0)
__device__ __forceinline__ float tanh_fast(float x) {
    float y = fminf(fmaxf(x, -9.0f), 9.0f);
    float t = exp2f(y * 2.8853901817f);      // e^(2y)
    return (t - 1.0f) * __builtin_amdgcn_rcpf(t + 1.0f);
}

// ---------------- Phase 1: gather + histogram (lane-per-token) ----------------
template <bool PARTIAL>
__global__ __launch_bounds__(256, 4)
void drmm_hist(const int* __restrict__ doc,
               const int* __restrict__ query,
               const float* __restrict__ emb,
               float* __restrict__ hist_out)
{
    __shared__ float histw[4][8][32];   // [wave][q][bin(+2 pad)]
    __shared__ float qn_s[8];

    const int tid  = threadIdx.x;
    const int bid  = blockIdx.x;        // (bd, token-half)
    const int bd   = bid >> 1;
    const int b    = bid >> 5;          // bd >> 4
    const int wid  = tid >> 6;
    const int lane = tid & 63;

    for (int i = tid; i < 4 * 8 * 32; i += 256) ((float*)histw)[i] = 0.0f;

    // wave-uniform query row indices (scalarized)
    const int* qrow = query + b * 8;
    const int qi0 = __builtin_amdgcn_readfirstlane(qrow[0]);
    const int qi1 = __builtin_amdgcn_readfirstlane(qrow[1]);
    const int qi2 = __builtin_amdgcn_readfirstlane(qrow[2]);
    const int qi3 = __builtin_amdgcn_readfirstlane(qrow[3]);
    const int qi4 = __builtin_amdgcn_readfirstlane(qrow[4]);
    const int qi5 = __builtin_amdgcn_readfirstlane(qrow[5]);
    const int qi6 = __builtin_amdgcn_readfirstlane(qrow[6]);
    const int qi7 = __builtin_amdgcn_readfirstlane(qrow[7]);

    const float4* qf0 = (const float4*)(emb + (size_t)qi0 * 128);
    const float4* qf1 = (const float4*)(emb + (size_t)qi1 * 128);
    const float4* qf2 = (const float4*)(emb + (size_t)qi2 * 128);
    const float4* qf3 = (const float4*)(emb + (size_t)qi3 * 128);
    const float4* qf4 = (const float4*)(emb + (size_t)qi4 * 128);
    const float4* qf5 = (const float4*)(emb + (size_t)qi5 * 128);
    const float4* qf6 = (const float4*)(emb + (size_t)qi6 * 128);
    const float4* qf7 = (const float4*)(emb + (size_t)qi7 * 128);

    // query norms: wave 0 (same op order as rounds 5-6; absmax was 0.0)
    if (wid == 0) {
        int q = lane >> 3, j = lane & 7;
        int qis = sel8i(qi0, qi1, qi2, qi3, qi4, qi5, qi6, qi7, q);
        const float4* qq = (const float4*)(emb + (size_t)qis * 128) + j * 4;
        float s = 0.f;
#pragma unroll
        for (int c = 0; c < 4; ++c) {
            float4 x = qq[c];
            s = fmaf(x.x, x.x, s); s = fmaf(x.y, x.y, s);
            s = fmaf(x.z, x.z, s); s = fmaf(x.w, x.w, s);
        }
        s += shflx(s, 1); s += shflx(s, 2); s += shflx(s, 4);
        if (j == 0) qn_s[q] = sqrtf(s);
    }
    __syncthreads();

    // ---- per-lane token streaming with 8-deep ping-pong prefetch ----
    const int gtok = bid * 256 + tid;          // 0..262143
    const int idx  = doc[gtok];
    const float4* rp = (const float4*)(emb + (size_t)idx * 128);

    float dd = 0.f;
    float dq0 = 0.f, dq1 = 0.f, dq2 = 0.f, dq3 = 0.f;
    float dq4 = 0.f, dq5 = 0.f, dq6 = 0.f, dq7 = 0.f;

    float4 vb[8];
#pragma unroll
    for (int p = 0; p < 8; ++p) vb[p] = rp[p];   // chunk 0 in flight

#pragma unroll
    for (int c = 0; c < 4; ++c) {
        float4 nb[8];
        if (c < 3) {
#pragma unroll
            for (int p = 0; p < 8; ++p) nb[p] = rp[(c + 1) * 8 + p];
        }
#pragma unroll
        for (int p = 0; p < 8; ++p) {
            const int s = c * 8 + p;
            float4 v  = vb[p];
            float4 a0 = qf0[s], a1 = qf1[s], a2 = qf2[s], a3 = qf3[s];
            float4 a4 = qf4[s], a5 = qf5[s], a6 = qf6[s], a7 = qf7[s];
            dd  = fmaf(v.x, v.x, dd);  dd  = fmaf(v.y, v.y, dd);
            dd  = fmaf(v.z, v.z, dd);  dd  = fmaf(v.w, v.w, dd);
#define ACC(A, Dq) Dq = fmaf(v.x, A.x, Dq); Dq = fmaf(v.y, A.y, Dq); \
                   Dq = fmaf(v.z, A.z, Dq); Dq = fmaf(v.w, A.w, Dq);
            ACC(a0, dq0) ACC(a1, dq1) ACC(a2, dq2) ACC(a3, dq3)
            ACC(a4, dq4) ACC(a5, dq5) ACC(a6, dq6) ACC(a7, dq7)
#undef ACC
        }
        if (c < 3) {
#pragma unroll
            for (int p = 0; p < 8; ++p) vb[p] = nb[p];
        }
    }

    const float dn = sqrtf(dd);
#define DOBIN(J, DQ) {                                                  \
        float sim = DQ / (dn * qn_s[J] + 1e-8f);                        \
        float u = (sim - 0.001f) / 0.999f * 30.0f;                      \
        int bin = (int)floorf(u);                                       \
        bin = bin < 0 ? 0 : (bin > 29 ? 29 : bin);                      \
        atomicAdd(&histw[wid][J][bin], 1.0f);                           \
    }
    DOBIN(0, dq0) DOBIN(1, dq1) DOBIN(2, dq2) DOBIN(3, dq3)
    DOBIN(4, dq4) DOBIN(5, dq5) DOBIN(6, dq6) DOBIN(7, dq7)
#undef DOBIN
    __syncthreads();

    // flush 8q x 30 bins (exact integer counts)
    if (tid < 240) {
        int q = tid / 30, k = tid - q * 30;
        float s = histw[0][q][k] + histw[1][q][k]
                + histw[2][q][k] + histw[3][q][k];
        if (PARTIAL) {
            hist_out[(size_t)bid * 240 + tid] = s;
        } else {
            atomicAdd(&hist_out[bd * 240 + tid], s);
        }
    }
}

// ---------------- Phase 2: gate softmax + MLP + output ----------------
template <bool PARTIAL>
__global__ __launch_bounds__(512, 4)
void drmm_mlp(const float* __restrict__ hist_g,
              const int* __restrict__ query,
              const float* __restrict__ idf,
              const float* __restrict__ w_gate,
              const float* __restrict__ g_in, const float* __restrict__ b_in,
              const float* __restrict__ W0, const float* __restrict__ b0,
              const float* __restrict__ g0, const float* __restrict__ be0,
              const float* __restrict__ W1, const float* __restrict__ b1,
              const float* __restrict__ g1, const float* __restrict__ be1,
              const float* __restrict__ W2, const float* __restrict__ b2,
              const float* __restrict__ g2, const float* __restrict__ be2,
              const float* __restrict__ W3, const float* __restrict__ b3,
              const float* __restrict__ g3, const float* __restrict__ be3,
              float* __restrict__ out)
{
    __shared__ float xrow[8][30];
    __shared__ float h1s[8][128];
    __shared__ float h2s[8][64];
    __shared__ float h3s[8][32];
    __shared__ float gate_s[8];
    __shared__ float part[8];

    const int tid  = threadIdx.x;
    const int bd   = blockIdx.x;
    const int b    = bd >> 4;
    const int wid  = tid >> 6;
    const int lane = tid & 63;

    // Gate softmax: 8 parallel lanes (same op order as rounds 2-6).
    if (tid >= 504) {
        int q = tid - 504;
        float z = w_gate[q] * idf[query[b * 8 + q]];
        float m = z;
        m = fmaxf(m, shflx(m, 1)); m = fmaxf(m, shflx(m, 2)); m = fmaxf(m, shflx(m, 4));
        float e = expf(z - m);
        float s = e;
        s += shflx(s, 1); s += shflx(s, 2); s += shflx(s, 4);
        gate_s[q] = e / s;
    }

    if (tid < 240) {
        int q = tid / 30, k = tid - q * 30;
        float s;
        if (PARTIAL) {
            const float* hp = hist_g + (size_t)bd * 480 + tid;
            s = hp[0] + hp[240];  // exact int counts
        } else {
            s = hist_g[bd * 240 + tid];
        }
        xrow[q][k] = g_in[k] * (s * BN_INV) + b_in[k];
    }
    __syncthreads();

    // layer 1: 30 -> 128 (lane j computes outputs j and j+64); wave wid = q
    {
        float a0 = 0.f, a1 = 0.f;
#pragma unroll
        for (int k = 0; k < 30; ++k) {
            float xk = xrow[wid][k];
            a0 += xk * W0[k * 128 + lane];
            a1 += xk * W0[k * 128 + 64 + lane];
        }
        a0 += b0[lane]; a1 += b0[lane + 64];
        h1s[wid][lane]      = tanh_fast(g0[lane]      * (a0 * BN_INV) + be0[lane]);
        h1s[wid][lane + 64] = tanh_fast(g0[lane + 64] * (a1 * BN_INV) + be0[lane + 64]);
    }
    __syncthreads();

    // layer 2: 128 -> 64
    {
        float a = 0.f;
#pragma unroll 8
        for (int k = 0; k < 128; ++k) a += h1s[wid][k] * W1[k * 64 + lane];
        a += b1[lane];
        h2s[wid][lane] = tanh_fast(g1[lane] * (a * BN_INV) + be1[lane]);
    }
    __syncthreads();

    // layer 3: 64 -> 32
    if (lane < 32) {
        float a = 0.f;
#pragma unroll 8
        for (int k = 0; k < 64; ++k) a += h2s[wid][k] * W2[k * 32 + lane];
        a += b2[lane];
        h3s[wid][lane] = tanh_fast(g2[lane] * (a * BN_INV) + be2[lane]);
    }
    __syncthreads();

    // layer 4: 32 -> 1, gate weighting
    if (lane == 0) {
        float a = 0.f;
#pragma unroll
        for (int k = 0; k < 32; ++k) a += h3s[wid][k] * W3[k];
        a += b3[0];
        float y = tanh_fast(g3[0] * (a * BN_INV) + be3[0]);
        part[wid] = gate_s[wid] * y;
    }
    __syncthreads();

    if (tid == 0) {
        float s = 0.f;
#pragma unroll
        for (int q = 0; q < 8; ++q) s += part[q];
        out[bd] = s;
    }
}

extern "C" void kernel_launch(void* const* d_in, const int* in_sizes, int n_in,
                              void* d_out, int out_size, void* d_ws, size_t ws_size,
                              hipStream_t stream) {
    (void)in_sizes; (void)n_in; (void)out_size;
    const int*   doc    = (const int*)d_in[0];
    const int*   query  = (const int*)d_in[1];
    const float* emb    = (const float*)d_in[2];
    const float* idf    = (const float*)d_in[3];
    const float* w_gate = (const float*)d_in[4];
    const float* g_in   = (const float*)d_in[5];
    const float* b_in   = (const float*)d_in[6];
    const float* W0  = (const float*)d_in[7];
    const float* b0  = (const float*)d_in[8];
    const float* g0  = (const float*)d_in[9];
    const float* be0 = (const float*)d_in[10];
    const float* W1  = (const float*)d_in[11];
    const float* b1  = (const float*)d_in[12];
    const float* g1  = (const float*)d_in[13];
    const float* be1 = (const float*)d_in[14];
    const float* W2  = (const float*)d_in[15];
    const float* b2  = (const float*)d_in[16];
    const float* g2  = (const float*)d_in[17];
    const float* be2 = (const float*)d_in[18];
    const float* W3  = (const float*)d_in[19];
    const float* b3  = (const float*)d_in[20];
    const float* g3  = (const float*)d_in[21];
    const float* be3 = (const float*)d_in[22];

    float* hist_g = (float*)d_ws;
    const size_t need_partial = (size_t)1024 * 240 * sizeof(float); // 983 KB

    if (ws_size >= need_partial) {
        drmm_hist<true><<<dim3(1024), dim3(256), 0, stream>>>(doc, query, emb, hist_g);
        drmm_mlp<true><<<dim3(512), dim3(512), 0, stream>>>(
            hist_g, query, idf, w_gate, g_in, b_in,
            W0, b0, g0, be0, W1, b1, g1, be1,
            W2, b2, g2, be2, W3, b3, g3, be3, (float*)d_out);
    } else {
        hipMemsetAsync(hist_g, 0, 512 * 240 * sizeof(float), stream);
        drmm_hist<false><<<dim3(1024), dim3(256), 0, stream>>>(doc, query, emb, hist_g);
        drmm_mlp<false><<<dim3(512), dim3(512), 0, stream>>>(
            hist_g, query, idf, w_gate, g_in, b_in,
            W0, b0, g0, be0, W1, b1, g1, be1,
            W2, b2, g2, be2, W3, b3, g3, be3, (float*)d_out);
    }
}